// Round 4
// baseline (709.064 us; speedup 1.0000x reference)
//
#include <hip/hip_runtime.h>

// SGC-Res: out = LayerNorm( (A @ feat) @ W^T + b )
// Identity: (A @ F) @ W^T = A @ (F @ W^T) = A @ G.
// Pipeline (no global atomics with return anywhere):
//   k_bhist:  per-block LDS histogram of edges over row-buckets (64 rows/bkt),
//             written to hist2d[blk][bkt] (coalesced plain stores)
//   k_bscan:  per-bucket exclusive scan of hist2d column across blocks
//   k_scanb2: exclusive scan of bucket totals -> bbase[]
//   k_bscat:  replay: slot = bbase[bkt] + hist2d[blk][bkt] + LDS-rank;
//             plain 8B store of packed (lrow,col,val)
//   k_gemm:   G = F @ W^T  (overwrites hist2d region - dead by then)
//   k_bnode:  one block per bucket: LDS f32 accumulators (64x64),
//             scalarized edge loop + ds_add_f32 (fire-and-forget),
//             then fused bias + LayerNorm + coalesced store.

typedef unsigned int u32;
typedef unsigned long long u64;
#define RFL(x) __builtin_amdgcn_readfirstlane(x)

#define EPB 2048    // edges per binning block (8 per thread)
#define MAXBK 2048  // bucket capacity in LDS (supports N <= 131072)

__global__ __launch_bounds__(256) void k_bhist(const int* __restrict__ row,
                                               u32* __restrict__ hist2d,
                                               int E, int NBK) {
    __shared__ u32 cnt[MAXBK];
    for (int i = threadIdx.x; i < NBK; i += 256) cnt[i] = 0;
    __syncthreads();
    int e0 = blockIdx.x * EPB;
#pragma unroll
    for (int j = 0; j < EPB / 256; ++j) {
        int e = e0 + j * 256 + threadIdx.x;
        if (e < E) atomicAdd(&cnt[(u32)row[e] >> 6], 1u);  // LDS, no return
    }
    __syncthreads();
    u32* dst = hist2d + (size_t)blockIdx.x * NBK;
    for (int i = threadIdx.x; i < NBK; i += 256) dst[i] = cnt[i];
}

// 256-thread block exclusive scan helper (all threads must participate).
__device__ __forceinline__ u32 blk_scan256(u32 v, u32* wsum, u32& total) {
    int lane = threadIdx.x & 63, wid = threadIdx.x >> 6;
    u32 incl = v;
#pragma unroll
    for (int o = 1; o < 64; o <<= 1) {
        u32 u = __shfl_up(incl, o);
        if (lane >= o) incl += u;
    }
    if (lane == 63) wsum[wid] = incl;
    __syncthreads();
    u32 woff = 0;
    for (int w = 0; w < wid; ++w) woff += wsum[w];
    total = wsum[0] + wsum[1] + wsum[2] + wsum[3];
    __syncthreads();
    return woff + incl - v;  // exclusive prefix
}

// One block per bucket: exclusive scan of hist2d[:, bkt] across blocks.
__global__ __launch_bounds__(256) void k_bscan(u32* __restrict__ hist2d,
                                               u32* __restrict__ btot,
                                               int NBLK, int NBK) {
    __shared__ u32 wsum[4];
    int bkt = blockIdx.x;
    u32 carry = 0;
    for (int r = 0; r < NBLK; r += 256) {
        int blk = r + threadIdx.x;
        u32 v = (blk < NBLK) ? hist2d[(size_t)blk * NBK + bkt] : 0;
        u32 tot;
        u32 ex = blk_scan256(v, wsum, tot);
        if (blk < NBLK) hist2d[(size_t)blk * NBK + bkt] = ex + carry;
        carry += tot;
    }
    if (threadIdx.x == 0) btot[bkt] = carry;
}

__global__ __launch_bounds__(256) void k_scanb2(const u32* __restrict__ btot,
                                                u32* __restrict__ bbase,
                                                int NBK, int E) {
    __shared__ u32 wsum[4];
    u32 carry = 0;
    for (int r = 0; r < NBK; r += 256) {
        int i = r + threadIdx.x;
        u32 v = (i < NBK) ? btot[i] : 0;
        u32 tot;
        u32 ex = blk_scan256(v, wsum, tot);
        if (i < NBK) bbase[i] = ex + carry;
        carry += tot;
    }
    if (threadIdx.x == 0) bbase[NBK] = (u32)E;
}

__global__ __launch_bounds__(256) void k_bscat(const int* __restrict__ row,
                                               const int* __restrict__ col,
                                               const float* __restrict__ vals,
                                               const u32* __restrict__ hist2d,
                                               const u32* __restrict__ bbase,
                                               u64* __restrict__ epair,
                                               int E, int NBK) {
    __shared__ u32 lbase[MAXBK];
    __shared__ u32 lcnt[MAXBK];
    const u32* hrow = hist2d + (size_t)blockIdx.x * NBK;
    for (int i = threadIdx.x; i < NBK; i += 256) {
        lbase[i] = bbase[i] + hrow[i];  // coalesced global reads
        lcnt[i] = 0;
    }
    __syncthreads();
    int e0 = blockIdx.x * EPB;
#pragma unroll
    for (int j = 0; j < EPB / 256; ++j) {
        int e = e0 + j * 256 + threadIdx.x;
        if (e < E) {
            u32 r = (u32)row[e];
            u32 bkt = r >> 6;
            u32 lrank = atomicAdd(&lcnt[bkt], 1u);      // LDS atomic, ~fast
            u32 pos = lbase[bkt] + lrank;
            u32 meta = (u32)col[e] | ((r & 63u) << 26); // col < 2^26
            epair[pos] = (u64)meta | ((u64)__float_as_uint(vals[e]) << 32);
        }
    }
}

// Dense G = F @ W^T. 256 thr = 4 waves, 64 nodes/block; W row in VGPRs.
__global__ __launch_bounds__(256) void k_gemm(const float* __restrict__ feat,
                                              const float* __restrict__ W,
                                              float* __restrict__ G, int N) {
    __shared__ float fs[4096];
    int lane = threadIdx.x & 63, wid = threadIdx.x >> 6;
    int n0 = blockIdx.x * 64;
    int valid = N - n0; if (valid > 64) valid = 64;
    int elems = valid * 64;
    for (int idx = threadIdx.x * 4; idx < elems; idx += 1024)
        *reinterpret_cast<float4*>(&fs[idx]) =
            *reinterpret_cast<const float4*>(&feat[(size_t)n0 * 64 + idx]);
    float wr[64];
#pragma unroll
    for (int d4 = 0; d4 < 16; ++d4) {
        float4 w4 = *reinterpret_cast<const float4*>(&W[lane * 64 + d4 * 4]);
        wr[d4 * 4 + 0] = w4.x; wr[d4 * 4 + 1] = w4.y;
        wr[d4 * 4 + 2] = w4.z; wr[d4 * 4 + 3] = w4.w;
    }
    __syncthreads();
    for (int j = 0; j < 16; ++j) {
        int r = wid * 16 + j;
        if (r >= valid) break;
        float o = 0.f;
#pragma unroll
        for (int d4 = 0; d4 < 16; ++d4) {
            float4 h4 = *reinterpret_cast<const float4*>(&fs[r * 64 + d4 * 4]);
            o = fmaf(h4.x, wr[d4 * 4 + 0], o);
            o = fmaf(h4.y, wr[d4 * 4 + 1], o);
            o = fmaf(h4.z, wr[d4 * 4 + 2], o);
            o = fmaf(h4.w, wr[d4 * 4 + 3], o);
        }
        G[(size_t)(n0 + r) * 64 + lane] = o;
    }
}

// One block per 64-row bucket. LDS f32 accumulators; lane = class dim.
__global__ __launch_bounds__(256) void k_bnode(
    const float* __restrict__ G, const u64* __restrict__ epair,
    const u32* __restrict__ bbase, const float* __restrict__ bias,
    const float* __restrict__ gamma, const float* __restrict__ beta,
    float* __restrict__ out, int N)
{
    __shared__ float hacc[64 * 64];
    int lane = threadIdx.x & 63, wid = threadIdx.x >> 6;
    for (int i = threadIdx.x * 4; i < 64 * 64; i += 1024)
        *reinterpret_cast<float4*>(&hacc[i]) = make_float4(0.f, 0.f, 0.f, 0.f);
    __syncthreads();

    int bkt = blockIdx.x;
    int s = RFL(bbase[bkt]);
    int t = RFL(bbase[bkt + 1]);
    int chunk = (t - s + 3) >> 2;
    int i0 = s + wid * chunk;
    int i1 = i0 + chunk; if (i1 > t) i1 = t;

    int i = i0;
    for (; i + 4 <= i1; i += 4) {
        u64 p0 = epair[i], p1 = epair[i + 1], p2 = epair[i + 2], p3 = epair[i + 3];
        u32 m0 = RFL((u32)p0), b0 = RFL((u32)(p0 >> 32));
        u32 m1 = RFL((u32)p1), b1 = RFL((u32)(p1 >> 32));
        u32 m2 = RFL((u32)p2), b2 = RFL((u32)(p2 >> 32));
        u32 m3 = RFL((u32)p3), b3 = RFL((u32)(p3 >> 32));
        float g0 = G[((size_t)(m0 & 0x03FFFFFFu) << 6) | lane];
        float g1 = G[((size_t)(m1 & 0x03FFFFFFu) << 6) | lane];
        float g2 = G[((size_t)(m2 & 0x03FFFFFFu) << 6) | lane];
        float g3 = G[((size_t)(m3 & 0x03FFFFFFu) << 6) | lane];
        atomicAdd(&hacc[((m0 >> 26) << 6) | lane], __uint_as_float(b0) * g0);
        atomicAdd(&hacc[((m1 >> 26) << 6) | lane], __uint_as_float(b1) * g1);
        atomicAdd(&hacc[((m2 >> 26) << 6) | lane], __uint_as_float(b2) * g2);
        atomicAdd(&hacc[((m3 >> 26) << 6) | lane], __uint_as_float(b3) * g3);
    }
    for (; i < i1; ++i) {
        u64 p = epair[i];
        u32 m = RFL((u32)p), b = RFL((u32)(p >> 32));
        float g = G[((size_t)(m & 0x03FFFFFFu) << 6) | lane];
        atomicAdd(&hacc[((m >> 26) << 6) | lane], __uint_as_float(b) * g);
    }
    __syncthreads();

    int rbase = bkt << 6;
#pragma unroll
    for (int j = 0; j < 16; ++j) {
        int r = wid * 16 + j;
        int n = rbase + r;
        if (n >= N) break;
        float o = hacc[(r << 6) | lane] + bias[lane];
        float ssum = o;
#pragma unroll
        for (int off = 32; off; off >>= 1) ssum += __shfl_xor(ssum, off);
        float mu = ssum * 0.015625f;
        float dv = o - mu;
        float vs = dv * dv;
#pragma unroll
        for (int off = 32; off; off >>= 1) vs += __shfl_xor(vs, off);
        float inv = rsqrtf(vs * 0.015625f + 1e-5f);
        out[((size_t)n << 6) + lane] = dv * inv * gamma[lane] + beta[lane];
    }
}

extern "C" void kernel_launch(void* const* d_in, const int* in_sizes, int n_in,
                              void* d_out, int out_size, void* d_ws, size_t ws_size,
                              hipStream_t stream) {
    const float* feat  = (const float*)d_in[0];
    // d_in[1] = feat_ori: dead code in reference, unused
    const int*   row   = (const int*)d_in[2];
    const int*   col   = (const int*)d_in[3];
    const float* vals  = (const float*)d_in[4];
    const float* W     = (const float*)d_in[5];
    const float* bias  = (const float*)d_in[6];
    const float* gamma = (const float*)d_in[7];
    const float* beta  = (const float*)d_in[8];
    float* out = (float*)d_out;

    const int D = 64;
    int N = in_sizes[0] / D;   // 100000 (NBK=1563 <= MAXBK)
    int E = in_sizes[2];

    int NBK  = (N + 63) / 64;       // buckets of 64 rows
    int NBLK = (E + EPB - 1) / EPB; // binning blocks

    // ws layout: [ G (N*64 f32) | epair (E u64) | btot | bbase ]
    // hist2d (NBLK*NBK u32) aliases the FRONT of G: it is dead before
    // k_gemm writes G. (hist2d bytes = NBLK*NBK*4 << N*256 bytes.)
    char* ws = (char*)d_ws;
    float* G      = (float*)ws;
    u32*   hist2d = (u32*)ws;
    size_t eoff   = ((size_t)N * 256 + 255) & ~(size_t)255;
    u64*   epair  = (u64*)(ws + eoff);
    size_t boff   = eoff + (size_t)E * 8;
    u32*   btot   = (u32*)(ws + boff);
    u32*   bbase  = btot + NBK;   // NBK+1 entries

    k_bhist <<<NBLK, 256, 0, stream>>>(row, hist2d, E, NBK);
    k_bscan <<<NBK, 256, 0, stream>>>(hist2d, btot, NBLK, NBK);
    k_scanb2<<<1, 256, 0, stream>>>(btot, bbase, NBK, E);
    k_bscat <<<NBLK, 256, 0, stream>>>(row, col, vals, hist2d, bbase,
                                       epair, E, NBK);
    k_gemm  <<<(N + 63) / 64, 256, 0, stream>>>(feat, W, G, N);
    k_bnode <<<NBK, 256, 0, stream>>>(G, epair, bbase, bias, gamma, beta,
                                      out, N);
}

// Round 5
// 175.384 us; speedup vs baseline: 4.0429x; 4.0429x over previous
//
#include <hip/hip_runtime.h>

// SGC-Res: out = LayerNorm( (A @ feat) @ W^T + b )
// Identity: (A @ F) @ W^T = A @ (F @ W^T) = A @ G.
// Pipeline (no global return-atomics, no f32 LDS atomics):
//   k_bhist:   per-block LDS histogram over row-buckets (64 rows/bkt)
//   k_bscan:   per-bucket exclusive scan of hist2d column across blocks
//   k_scanb2:  exclusive scan of bucket totals -> bbase[]
//   k_bscat:   bucket-ordered scatter: epair1 = (lrow|col, val), plain stores
//   k_regroup: per-bucket block: LDS u32 hist of 64 local rows + shfl scan
//              -> CSR epair2 (plain stores) + offs2[n] row starts
//   k_gemm:    G = F @ W^T   (G aliases epair1's region - dead by then)
//   k_node:    per-node wave (25000 blocks): scalarized edge loop, register
//              accumulate, fused bias + LayerNorm + store.

typedef unsigned int u32;
typedef unsigned long long u64;
#define RFL(x) __builtin_amdgcn_readfirstlane(x)

#define EPB 2048    // edges per binning block (8 per thread)
#define MAXBK 2048  // bucket capacity in LDS (supports N <= 131072)

__global__ __launch_bounds__(256) void k_bhist(const int* __restrict__ row,
                                               u32* __restrict__ hist2d,
                                               int E, int NBK) {
    __shared__ u32 cnt[MAXBK];
    for (int i = threadIdx.x; i < NBK; i += 256) cnt[i] = 0;
    __syncthreads();
    int e0 = blockIdx.x * EPB;
#pragma unroll
    for (int j = 0; j < EPB / 256; ++j) {
        int e = e0 + j * 256 + threadIdx.x;
        if (e < E) atomicAdd(&cnt[(u32)row[e] >> 6], 1u);  // LDS u32, no rtn
    }
    __syncthreads();
    u32* dst = hist2d + (size_t)blockIdx.x * NBK;
    for (int i = threadIdx.x; i < NBK; i += 256) dst[i] = cnt[i];
}

__device__ __forceinline__ u32 blk_scan256(u32 v, u32* wsum, u32& total) {
    int lane = threadIdx.x & 63, wid = threadIdx.x >> 6;
    u32 incl = v;
#pragma unroll
    for (int o = 1; o < 64; o <<= 1) {
        u32 u = __shfl_up(incl, o);
        if (lane >= o) incl += u;
    }
    if (lane == 63) wsum[wid] = incl;
    __syncthreads();
    u32 woff = 0;
    for (int w = 0; w < wid; ++w) woff += wsum[w];
    total = wsum[0] + wsum[1] + wsum[2] + wsum[3];
    __syncthreads();
    return woff + incl - v;  // exclusive prefix
}

__global__ __launch_bounds__(256) void k_bscan(u32* __restrict__ hist2d,
                                               u32* __restrict__ btot,
                                               int NBLK, int NBK) {
    __shared__ u32 wsum[4];
    int bkt = blockIdx.x;
    u32 carry = 0;
    for (int r = 0; r < NBLK; r += 256) {
        int blk = r + threadIdx.x;
        u32 v = (blk < NBLK) ? hist2d[(size_t)blk * NBK + bkt] : 0;
        u32 tot;
        u32 ex = blk_scan256(v, wsum, tot);
        if (blk < NBLK) hist2d[(size_t)blk * NBK + bkt] = ex + carry;
        carry += tot;
    }
    if (threadIdx.x == 0) btot[bkt] = carry;
}

__global__ __launch_bounds__(256) void k_scanb2(const u32* __restrict__ btot,
                                                u32* __restrict__ bbase,
                                                int NBK, int E) {
    __shared__ u32 wsum[4];
    u32 carry = 0;
    for (int r = 0; r < NBK; r += 256) {
        int i = r + threadIdx.x;
        u32 v = (i < NBK) ? btot[i] : 0;
        u32 tot;
        u32 ex = blk_scan256(v, wsum, tot);
        if (i < NBK) bbase[i] = ex + carry;
        carry += tot;
    }
    if (threadIdx.x == 0) bbase[NBK] = (u32)E;
}

__global__ __launch_bounds__(256) void k_bscat(const int* __restrict__ row,
                                               const int* __restrict__ col,
                                               const float* __restrict__ vals,
                                               const u32* __restrict__ hist2d,
                                               const u32* __restrict__ bbase,
                                               u64* __restrict__ epair1,
                                               int E, int NBK) {
    __shared__ u32 lbase[MAXBK];
    __shared__ u32 lcnt[MAXBK];
    const u32* hrow = hist2d + (size_t)blockIdx.x * NBK;
    for (int i = threadIdx.x; i < NBK; i += 256) {
        lbase[i] = bbase[i] + hrow[i];
        lcnt[i] = 0;
    }
    __syncthreads();
    int e0 = blockIdx.x * EPB;
#pragma unroll
    for (int j = 0; j < EPB / 256; ++j) {
        int e = e0 + j * 256 + threadIdx.x;
        if (e < E) {
            u32 r = (u32)row[e];
            u32 bkt = r >> 6;
            u32 lrank = atomicAdd(&lcnt[bkt], 1u);      // LDS u32 rtn, fast
            u32 pos = lbase[bkt] + lrank;
            u32 meta = (u32)col[e] | ((r & 63u) << 26); // col < 2^26
            epair1[pos] = (u64)meta | ((u64)__float_as_uint(vals[e]) << 32);
        }
    }
}

// Per bucket: group bucket's edges by local row -> CSR epair2 + offs2 starts.
__global__ __launch_bounds__(256) void k_regroup(const u64* __restrict__ epair1,
                                                 const u32* __restrict__ bbase,
                                                 u64* __restrict__ epair2,
                                                 u32* __restrict__ offs2,
                                                 int N, int E, int NBK) {
    __shared__ u32 cnt[64], base[64], cnt2[64];
    int tid = threadIdx.x;
    if (tid < 64) { cnt[tid] = 0; cnt2[tid] = 0; }
    __syncthreads();
    int bkt = blockIdx.x;
    int s = RFL(bbase[bkt]);
    int t = RFL(bbase[bkt + 1]);
    // pass 1: count local rows (read only low word of each pair)
    const u32* meta1 = (const u32*)epair1;
    for (int i = s + tid; i < t; i += 256)
        atomicAdd(&cnt[meta1[2 * (size_t)i] >> 26], 1u);
    __syncthreads();
    // wave 0: 64-lane exclusive scan of cnt -> base; emit row starts
    if (tid < 64) {
        u32 v = cnt[tid];
        u32 incl = v;
#pragma unroll
        for (int o = 1; o < 64; o <<= 1) {
            u32 u = __shfl_up(incl, o);
            if (tid >= o) incl += u;
        }
        u32 ex = incl - v;
        base[tid] = ex;
        int n = (bkt << 6) + tid;
        if (n < N) offs2[n] = (u32)s + ex;
    }
    if (bkt == 0 && tid == 0) offs2[N] = (u32)E;
    __syncthreads();
    // pass 2: scatter into CSR slots (plain stores)
    for (int i = s + tid; i < t; i += 256) {
        u64 p = epair1[i];
        u32 m = (u32)p;
        u32 r = m >> 26;
        u32 rank = atomicAdd(&cnt2[r], 1u);
        epair2[(size_t)s + base[r] + rank] =
            (p & 0xFFFFFFFF00000000ull) | (u64)(m & 0x03FFFFFFu);
    }
}

// Dense G = F @ W^T. 256 thr = 4 waves, 64 nodes/block; W row in VGPRs.
__global__ __launch_bounds__(256) void k_gemm(const float* __restrict__ feat,
                                              const float* __restrict__ W,
                                              float* __restrict__ G, int N) {
    __shared__ float fs[4096];
    int lane = threadIdx.x & 63, wid = threadIdx.x >> 6;
    int n0 = blockIdx.x * 64;
    int valid = N - n0; if (valid > 64) valid = 64;
    int elems = valid * 64;
    for (int idx = threadIdx.x * 4; idx < elems; idx += 1024)
        *reinterpret_cast<float4*>(&fs[idx]) =
            *reinterpret_cast<const float4*>(&feat[(size_t)n0 * 64 + idx]);
    float wr[64];
#pragma unroll
    for (int d4 = 0; d4 < 16; ++d4) {
        float4 w4 = *reinterpret_cast<const float4*>(&W[lane * 64 + d4 * 4]);
        wr[d4 * 4 + 0] = w4.x; wr[d4 * 4 + 1] = w4.y;
        wr[d4 * 4 + 2] = w4.z; wr[d4 * 4 + 3] = w4.w;
    }
    __syncthreads();
    for (int j = 0; j < 16; ++j) {
        int r = wid * 16 + j;
        if (r >= valid) break;
        float o = 0.f;
#pragma unroll
        for (int d4 = 0; d4 < 16; ++d4) {
            float4 h4 = *reinterpret_cast<const float4*>(&fs[r * 64 + d4 * 4]);
            o = fmaf(h4.x, wr[d4 * 4 + 0], o);
            o = fmaf(h4.y, wr[d4 * 4 + 1], o);
            o = fmaf(h4.z, wr[d4 * 4 + 2], o);
            o = fmaf(h4.w, wr[d4 * 4 + 3], o);
        }
        G[(size_t)(n0 + r) * 64 + lane] = o;
    }
}

// One 64-lane wave per node, lane = class c. Register accumulate, no LDS.
__global__ __launch_bounds__(256) void k_node(
    const float* __restrict__ G, const u64* __restrict__ epair2,
    const u32* __restrict__ offs2, const float* __restrict__ bias,
    const float* __restrict__ gamma, const float* __restrict__ beta,
    float* __restrict__ out, int N)
{
    int lane = threadIdx.x & 63;
    int n = (blockIdx.x << 2) + (threadIdx.x >> 6);
    if (n >= N) return;
    int start = RFL((int)offs2[n]);
    int end   = RFL((int)offs2[n + 1]);

    float acc0 = 0.f, acc1 = 0.f;
    int i = start;
    for (; i + 8 <= end; i += 8) {
        u64 p0 = epair2[i],     p1 = epair2[i + 1];
        u64 p2 = epair2[i + 2], p3 = epair2[i + 3];
        u64 p4 = epair2[i + 4], p5 = epair2[i + 5];
        u64 p6 = epair2[i + 6], p7 = epair2[i + 7];
        u32 c0 = RFL((u32)p0), b0 = RFL((u32)(p0 >> 32));
        u32 c1 = RFL((u32)p1), b1 = RFL((u32)(p1 >> 32));
        u32 c2 = RFL((u32)p2), b2 = RFL((u32)(p2 >> 32));
        u32 c3 = RFL((u32)p3), b3 = RFL((u32)(p3 >> 32));
        u32 c4 = RFL((u32)p4), b4 = RFL((u32)(p4 >> 32));
        u32 c5 = RFL((u32)p5), b5 = RFL((u32)(p5 >> 32));
        u32 c6 = RFL((u32)p6), b6 = RFL((u32)(p6 >> 32));
        u32 c7 = RFL((u32)p7), b7 = RFL((u32)(p7 >> 32));
        float g0 = G[((size_t)c0 << 6) | lane];
        float g1 = G[((size_t)c1 << 6) | lane];
        float g2 = G[((size_t)c2 << 6) | lane];
        float g3 = G[((size_t)c3 << 6) | lane];
        float g4 = G[((size_t)c4 << 6) | lane];
        float g5 = G[((size_t)c5 << 6) | lane];
        float g6 = G[((size_t)c6 << 6) | lane];
        float g7 = G[((size_t)c7 << 6) | lane];
        acc0 = fmaf(__uint_as_float(b0), g0, acc0);
        acc1 = fmaf(__uint_as_float(b1), g1, acc1);
        acc0 = fmaf(__uint_as_float(b2), g2, acc0);
        acc1 = fmaf(__uint_as_float(b3), g3, acc1);
        acc0 = fmaf(__uint_as_float(b4), g4, acc0);
        acc1 = fmaf(__uint_as_float(b5), g5, acc1);
        acc0 = fmaf(__uint_as_float(b6), g6, acc0);
        acc1 = fmaf(__uint_as_float(b7), g7, acc1);
    }
    for (; i < end; ++i) {
        u64 p = epair2[i];
        u32 c = RFL((u32)p), b = RFL((u32)(p >> 32));
        acc0 = fmaf(__uint_as_float(b), G[((size_t)c << 6) | lane], acc0);
    }
    float o = acc0 + acc1 + bias[lane];

    // LayerNorm over 64 lanes
    float s = o;
#pragma unroll
    for (int off = 32; off; off >>= 1) s += __shfl_xor(s, off);
    float mu = s * 0.015625f;
    float dv = o - mu;
    float vs = dv * dv;
#pragma unroll
    for (int off = 32; off; off >>= 1) vs += __shfl_xor(vs, off);
    float inv = rsqrtf(vs * 0.015625f + 1e-5f);
    out[((size_t)n << 6) + lane] = dv * inv * gamma[lane] + beta[lane];
}

extern "C" void kernel_launch(void* const* d_in, const int* in_sizes, int n_in,
                              void* d_out, int out_size, void* d_ws, size_t ws_size,
                              hipStream_t stream) {
    const float* feat  = (const float*)d_in[0];
    // d_in[1] = feat_ori: dead code in reference, unused
    const int*   row   = (const int*)d_in[2];
    const int*   col   = (const int*)d_in[3];
    const float* vals  = (const float*)d_in[4];
    const float* W     = (const float*)d_in[5];
    const float* bias  = (const float*)d_in[6];
    const float* gamma = (const float*)d_in[7];
    const float* beta  = (const float*)d_in[8];
    float* out = (float*)d_out;

    const int D = 64;
    int N = in_sizes[0] / D;   // 100000 (NBK = 1563 <= MAXBK)
    int E = in_sizes[2];

    int NBK  = (N + 63) / 64;
    int NBLK = (E + EPB - 1) / EPB;

    // ws layout (aliased to fit):
    //   Region A [0, N*256):       G (gemm output).  epair1 (E*8) lives at
    //                              its front - dead before k_gemm runs.
    //   Region B [A, A+E*8):       epair2.  hist2d (NBLK*NBK*4) lives at its
    //                              front - dead before k_regroup writes.
    //   Region C: btot (NBK), bbase (NBK+1), offs2 (N+1).
    char* ws = (char*)d_ws;
    float* G      = (float*)ws;
    u64*   epair1 = (u64*)ws;
    size_t boffB  = ((size_t)N * 256 + 255) & ~(size_t)255;
    u64*   epair2 = (u64*)(ws + boffB);
    u32*   hist2d = (u32*)(ws + boffB);
    size_t boffC  = boffB + ((size_t)E * 8 + 255 & ~(size_t)255);
    u32*   btot   = (u32*)(ws + boffC);
    u32*   bbase  = btot + NBK;          // NBK+1 entries
    u32*   offs2  = bbase + NBK + 1;     // N+1 entries

    k_bhist  <<<NBLK, 256, 0, stream>>>(row, hist2d, E, NBK);
    k_bscan  <<<NBK, 256, 0, stream>>>(hist2d, btot, NBLK, NBK);
    k_scanb2 <<<1, 256, 0, stream>>>(btot, bbase, NBK, E);
    k_bscat  <<<NBLK, 256, 0, stream>>>(row, col, vals, hist2d, bbase,
                                        epair1, E, NBK);
    k_regroup<<<NBK, 256, 0, stream>>>(epair1, bbase, epair2, offs2, N, E, NBK);
    k_gemm   <<<(N + 63) / 64, 256, 0, stream>>>(feat, W, G, N);
    k_node   <<<(N + 3) / 4, 256, 0, stream>>>(G, epair2, offs2,
                                               bias, gamma, beta, out, N);
}

// Round 6
// 166.373 us; speedup vs baseline: 4.2619x; 1.0542x over previous
//
#include <hip/hip_runtime.h>

// SGC-Res: out = LayerNorm( (A @ feat) @ W^T + b )
// Identity: (A @ F) @ W^T = A @ (F @ W^T) = A @ G.   G stored in BF16:
// halves the random-gather operand (12.8 MB -> fits aggregate L2) and the
// per-edge row read (128 B).  bf16->f32 is exact (u<<16); f32->bf16 is RNE.
// Pipeline (no global return-atomics, no f32 LDS atomics):
//   k_bhist:   per-block LDS histogram over row-buckets (64 rows/bkt)
//   k_bscan:   per-bucket exclusive scan of hist2d column across blocks
//   k_scanb2:  exclusive scan of bucket totals -> bbase[]
//   k_bscat:   bucket-ordered scatter: epair1 = (lrow|col, val), plain stores
//   k_regroup: per-bucket: LDS u32 hist of 64 local rows + shfl scan
//              -> CSR epair2 (plain stores) + offs2[n] row starts
//   k_gemm:    G(bf16) = F @ W^T   (G aliases epair1's region - dead by then)
//   k_node:    per-node wave (25000 blocks): scalarized edge loop, register
//              accumulate, fused bias + LayerNorm + store.

typedef unsigned int u32;
typedef unsigned short u16;
typedef unsigned long long u64;
#define RFL(x) __builtin_amdgcn_readfirstlane(x)

#define EPB 2048    // edges per binning block (8 per thread)
#define MAXBK 2048  // bucket capacity in LDS (supports N <= 131072)

__device__ __forceinline__ float bf2f(u16 v) {
    return __uint_as_float((u32)v << 16);
}
__device__ __forceinline__ u16 f2bf(float f) {
    u32 b = __float_as_uint(f);
    return (u16)((b + 0x7FFFu + ((b >> 16) & 1u)) >> 16);  // RNE
}

__global__ __launch_bounds__(256) void k_bhist(const int* __restrict__ row,
                                               u32* __restrict__ hist2d,
                                               int E, int NBK) {
    __shared__ u32 cnt[MAXBK];
    for (int i = threadIdx.x; i < NBK; i += 256) cnt[i] = 0;
    __syncthreads();
    int e0 = blockIdx.x * EPB;
#pragma unroll
    for (int j = 0; j < EPB / 256; ++j) {
        int e = e0 + j * 256 + threadIdx.x;
        if (e < E) atomicAdd(&cnt[(u32)row[e] >> 6], 1u);  // LDS u32, no rtn
    }
    __syncthreads();
    u32* dst = hist2d + (size_t)blockIdx.x * NBK;
    for (int i = threadIdx.x; i < NBK; i += 256) dst[i] = cnt[i];
}

__device__ __forceinline__ u32 blk_scan256(u32 v, u32* wsum, u32& total) {
    int lane = threadIdx.x & 63, wid = threadIdx.x >> 6;
    u32 incl = v;
#pragma unroll
    for (int o = 1; o < 64; o <<= 1) {
        u32 u = __shfl_up(incl, o);
        if (lane >= o) incl += u;
    }
    if (lane == 63) wsum[wid] = incl;
    __syncthreads();
    u32 woff = 0;
    for (int w = 0; w < wid; ++w) woff += wsum[w];
    total = wsum[0] + wsum[1] + wsum[2] + wsum[3];
    __syncthreads();
    return woff + incl - v;  // exclusive prefix
}

__global__ __launch_bounds__(256) void k_bscan(u32* __restrict__ hist2d,
                                               u32* __restrict__ btot,
                                               int NBLK, int NBK) {
    __shared__ u32 wsum[4];
    int bkt = blockIdx.x;
    u32 carry = 0;
    for (int r = 0; r < NBLK; r += 256) {
        int blk = r + threadIdx.x;
        u32 v = (blk < NBLK) ? hist2d[(size_t)blk * NBK + bkt] : 0;
        u32 tot;
        u32 ex = blk_scan256(v, wsum, tot);
        if (blk < NBLK) hist2d[(size_t)blk * NBK + bkt] = ex + carry;
        carry += tot;
    }
    if (threadIdx.x == 0) btot[bkt] = carry;
}

__global__ __launch_bounds__(256) void k_scanb2(const u32* __restrict__ btot,
                                                u32* __restrict__ bbase,
                                                int NBK, int E) {
    __shared__ u32 wsum[4];
    u32 carry = 0;
    for (int r = 0; r < NBK; r += 256) {
        int i = r + threadIdx.x;
        u32 v = (i < NBK) ? btot[i] : 0;
        u32 tot;
        u32 ex = blk_scan256(v, wsum, tot);
        if (i < NBK) bbase[i] = ex + carry;
        carry += tot;
    }
    if (threadIdx.x == 0) bbase[NBK] = (u32)E;
}

__global__ __launch_bounds__(256) void k_bscat(const int* __restrict__ row,
                                               const int* __restrict__ col,
                                               const float* __restrict__ vals,
                                               const u32* __restrict__ hist2d,
                                               const u32* __restrict__ bbase,
                                               u64* __restrict__ epair1,
                                               int E, int NBK) {
    __shared__ u32 lbase[MAXBK];
    __shared__ u32 lcnt[MAXBK];
    const u32* hrow = hist2d + (size_t)blockIdx.x * NBK;
    for (int i = threadIdx.x; i < NBK; i += 256) {
        lbase[i] = bbase[i] + hrow[i];
        lcnt[i] = 0;
    }
    __syncthreads();
    int e0 = blockIdx.x * EPB;
#pragma unroll
    for (int j = 0; j < EPB / 256; ++j) {
        int e = e0 + j * 256 + threadIdx.x;
        if (e < E) {
            u32 r = (u32)row[e];
            u32 bkt = r >> 6;
            u32 lrank = atomicAdd(&lcnt[bkt], 1u);      // LDS u32 rtn, fast
            u32 pos = lbase[bkt] + lrank;
            u32 meta = (u32)col[e] | ((r & 63u) << 26); // col < 2^26
            epair1[pos] = (u64)meta | ((u64)__float_as_uint(vals[e]) << 32);
        }
    }
}

// Per bucket: group bucket's edges by local row -> CSR epair2 + offs2 starts.
__global__ __launch_bounds__(256) void k_regroup(const u64* __restrict__ epair1,
                                                 const u32* __restrict__ bbase,
                                                 u64* __restrict__ epair2,
                                                 u32* __restrict__ offs2,
                                                 int N, int E, int NBK) {
    __shared__ u32 cnt[64], base[64], cnt2[64];
    int tid = threadIdx.x;
    if (tid < 64) { cnt[tid] = 0; cnt2[tid] = 0; }
    __syncthreads();
    int bkt = blockIdx.x;
    int s = RFL(bbase[bkt]);
    int t = RFL(bbase[bkt + 1]);
    // pass 1: count local rows (read only low word of each pair)
    const u32* meta1 = (const u32*)epair1;
    for (int i = s + tid; i < t; i += 256)
        atomicAdd(&cnt[meta1[2 * (size_t)i] >> 26], 1u);
    __syncthreads();
    // wave 0: 64-lane exclusive scan of cnt -> base; emit row starts
    if (tid < 64) {
        u32 v = cnt[tid];
        u32 incl = v;
#pragma unroll
        for (int o = 1; o < 64; o <<= 1) {
            u32 u = __shfl_up(incl, o);
            if (tid >= o) incl += u;
        }
        u32 ex = incl - v;
        base[tid] = ex;
        int n = (bkt << 6) + tid;
        if (n < N) offs2[n] = (u32)s + ex;
    }
    if (bkt == 0 && tid == 0) offs2[N] = (u32)E;
    __syncthreads();
    // pass 2: scatter into CSR slots (plain stores)
    for (int i = s + tid; i < t; i += 256) {
        u64 p = epair1[i];
        u32 m = (u32)p;
        u32 r = m >> 26;
        u32 rank = atomicAdd(&cnt2[r], 1u);
        epair2[(size_t)s + base[r] + rank] =
            (p & 0xFFFFFFFF00000000ull) | (u64)(m & 0x03FFFFFFu);
    }
}

// Dense G(bf16) = F @ W^T. 256 thr = 4 waves, 64 nodes/block; W in VGPRs.
__global__ __launch_bounds__(256) void k_gemm(const float* __restrict__ feat,
                                              const float* __restrict__ W,
                                              u16* __restrict__ G, int N) {
    __shared__ float fs[4096];
    int lane = threadIdx.x & 63, wid = threadIdx.x >> 6;
    int n0 = blockIdx.x * 64;
    int valid = N - n0; if (valid > 64) valid = 64;
    int elems = valid * 64;
    for (int idx = threadIdx.x * 4; idx < elems; idx += 1024)
        *reinterpret_cast<float4*>(&fs[idx]) =
            *reinterpret_cast<const float4*>(&feat[(size_t)n0 * 64 + idx]);
    float wr[64];
#pragma unroll
    for (int d4 = 0; d4 < 16; ++d4) {
        float4 w4 = *reinterpret_cast<const float4*>(&W[lane * 64 + d4 * 4]);
        wr[d4 * 4 + 0] = w4.x; wr[d4 * 4 + 1] = w4.y;
        wr[d4 * 4 + 2] = w4.z; wr[d4 * 4 + 3] = w4.w;
    }
    __syncthreads();
    for (int j = 0; j < 16; ++j) {
        int r = wid * 16 + j;
        if (r >= valid) break;
        float o = 0.f;
#pragma unroll
        for (int d4 = 0; d4 < 16; ++d4) {
            float4 h4 = *reinterpret_cast<const float4*>(&fs[r * 64 + d4 * 4]);
            o = fmaf(h4.x, wr[d4 * 4 + 0], o);
            o = fmaf(h4.y, wr[d4 * 4 + 1], o);
            o = fmaf(h4.z, wr[d4 * 4 + 2], o);
            o = fmaf(h4.w, wr[d4 * 4 + 3], o);
        }
        G[(size_t)(n0 + r) * 64 + lane] = f2bf(o);
    }
}

// One 64-lane wave per node, lane = class c. Register accumulate, no LDS.
__global__ __launch_bounds__(256) void k_node(
    const u16* __restrict__ G, const u64* __restrict__ epair2,
    const u32* __restrict__ offs2, const float* __restrict__ bias,
    const float* __restrict__ gamma, const float* __restrict__ beta,
    float* __restrict__ out, int N)
{
    int lane = threadIdx.x & 63;
    int n = (blockIdx.x << 2) + (threadIdx.x >> 6);
    if (n >= N) return;
    int start = RFL((int)offs2[n]);
    int end   = RFL((int)offs2[n + 1]);

    float acc0 = 0.f, acc1 = 0.f;
    int i = start;
    for (; i + 8 <= end; i += 8) {
        u64 p0 = epair2[i],     p1 = epair2[i + 1];
        u64 p2 = epair2[i + 2], p3 = epair2[i + 3];
        u64 p4 = epair2[i + 4], p5 = epair2[i + 5];
        u64 p6 = epair2[i + 6], p7 = epair2[i + 7];
        u32 c0 = RFL((u32)p0), b0 = RFL((u32)(p0 >> 32));
        u32 c1 = RFL((u32)p1), b1 = RFL((u32)(p1 >> 32));
        u32 c2 = RFL((u32)p2), b2 = RFL((u32)(p2 >> 32));
        u32 c3 = RFL((u32)p3), b3 = RFL((u32)(p3 >> 32));
        u32 c4 = RFL((u32)p4), b4 = RFL((u32)(p4 >> 32));
        u32 c5 = RFL((u32)p5), b5 = RFL((u32)(p5 >> 32));
        u32 c6 = RFL((u32)p6), b6 = RFL((u32)(p6 >> 32));
        u32 c7 = RFL((u32)p7), b7 = RFL((u32)(p7 >> 32));
        float g0 = bf2f(G[((size_t)c0 << 6) | lane]);
        float g1 = bf2f(G[((size_t)c1 << 6) | lane]);
        float g2 = bf2f(G[((size_t)c2 << 6) | lane]);
        float g3 = bf2f(G[((size_t)c3 << 6) | lane]);
        float g4 = bf2f(G[((size_t)c4 << 6) | lane]);
        float g5 = bf2f(G[((size_t)c5 << 6) | lane]);
        float g6 = bf2f(G[((size_t)c6 << 6) | lane]);
        float g7 = bf2f(G[((size_t)c7 << 6) | lane]);
        acc0 = fmaf(__uint_as_float(b0), g0, acc0);
        acc1 = fmaf(__uint_as_float(b1), g1, acc1);
        acc0 = fmaf(__uint_as_float(b2), g2, acc0);
        acc1 = fmaf(__uint_as_float(b3), g3, acc1);
        acc0 = fmaf(__uint_as_float(b4), g4, acc0);
        acc1 = fmaf(__uint_as_float(b5), g5, acc1);
        acc0 = fmaf(__uint_as_float(b6), g6, acc0);
        acc1 = fmaf(__uint_as_float(b7), g7, acc1);
    }
    for (; i < end; ++i) {
        u64 p = epair2[i];
        u32 c = RFL((u32)p), b = RFL((u32)(p >> 32));
        acc0 = fmaf(__uint_as_float(b), bf2f(G[((size_t)c << 6) | lane]), acc0);
    }
    float o = acc0 + acc1 + bias[lane];

    // LayerNorm over 64 lanes
    float s = o;
#pragma unroll
    for (int off = 32; off; off >>= 1) s += __shfl_xor(s, off);
    float mu = s * 0.015625f;
    float dv = o - mu;
    float vs = dv * dv;
#pragma unroll
    for (int off = 32; off; off >>= 1) vs += __shfl_xor(vs, off);
    float inv = rsqrtf(vs * 0.015625f + 1e-5f);
    out[((size_t)n << 6) + lane] = dv * inv * gamma[lane] + beta[lane];
}

extern "C" void kernel_launch(void* const* d_in, const int* in_sizes, int n_in,
                              void* d_out, int out_size, void* d_ws, size_t ws_size,
                              hipStream_t stream) {
    const float* feat  = (const float*)d_in[0];
    // d_in[1] = feat_ori: dead code in reference, unused
    const int*   row   = (const int*)d_in[2];
    const int*   col   = (const int*)d_in[3];
    const float* vals  = (const float*)d_in[4];
    const float* W     = (const float*)d_in[5];
    const float* bias  = (const float*)d_in[6];
    const float* gamma = (const float*)d_in[7];
    const float* beta  = (const float*)d_in[8];
    float* out = (float*)d_out;

    const int D = 64;
    int N = in_sizes[0] / D;   // 100000 (NBK = 1563 <= MAXBK)
    int E = in_sizes[2];

    int NBK  = (N + 63) / 64;
    int NBLK = (E + EPB - 1) / EPB;

    // ws layout (aliased to fit):
    //   Region A: G (bf16, N*128 B).  epair1 (E*8) shares it - dead before
    //             k_gemm runs.  size = max(N*128, E*8).
    //   Region B: epair2 (E*8).  hist2d (NBLK*NBK*4) lives at its front -
    //             dead before k_regroup writes epair2.
    //   Region C: btot (NBK), bbase (NBK+1), offs2 (N+1).
    char* ws = (char*)d_ws;
    u16*   G      = (u16*)ws;
    u64*   epair1 = (u64*)ws;
    size_t sizeA  = (size_t)N * 128;
    if ((size_t)E * 8 > sizeA) sizeA = (size_t)E * 8;
    size_t boffB  = (sizeA + 255) & ~(size_t)255;
    u64*   epair2 = (u64*)(ws + boffB);
    u32*   hist2d = (u32*)(ws + boffB);
    size_t boffC  = boffB + (((size_t)E * 8 + 255) & ~(size_t)255);
    u32*   btot   = (u32*)(ws + boffC);
    u32*   bbase  = btot + NBK;          // NBK+1 entries
    u32*   offs2  = bbase + NBK + 1;     // N+1 entries

    k_bhist  <<<NBLK, 256, 0, stream>>>(row, hist2d, E, NBK);
    k_bscan  <<<NBK, 256, 0, stream>>>(hist2d, btot, NBLK, NBK);
    k_scanb2 <<<1, 256, 0, stream>>>(btot, bbase, NBK, E);
    k_bscat  <<<NBLK, 256, 0, stream>>>(row, col, vals, hist2d, bbase,
                                        epair1, E, NBK);
    k_regroup<<<NBK, 256, 0, stream>>>(epair1, bbase, epair2, offs2, N, E, NBK);
    k_gemm   <<<(N + 63) / 64, 256, 0, stream>>>(feat, W, G, N);
    k_node   <<<(N + 3) / 4, 256, 0, stream>>>(G, epair2, offs2,
                                               bias, gamma, beta, out, N);
}